// Round 1
// baseline (47.354 us; speedup 1.0000x reference)
//
#include <hip/hip_runtime.h>

#define NUM_C  16
#define NUM_D  8
#define RECEPT 512
#define NWIN   128
#define LROW   32768
#define EPS_V  1e-4f

// x LDS region: 32768 + 256 (wrap replica) bf16 elements
#define XBYTES 66048
#define WBYTES 65536
#define LDS_TOTAL (XBYTES + WBYTES)

typedef __attribute__((ext_vector_type(8))) short short8;
typedef __attribute__((ext_vector_type(4))) float f32x4;

__device__ __forceinline__ unsigned short f2bf(float f) {
    unsigned int u = __builtin_bit_cast(unsigned int, f);
    u += 0x7fffu + ((u >> 16) & 1u);   // round-to-nearest-even
    return (unsigned short)(u >> 16);
}

// XOR swizzle on byte address within the 1-D x LDS buffer: spreads the
// 512B window-row stride across 8 distinct 16B slots (kills 16-way conflicts).
__device__ __forceinline__ int xsw(int a) { return a ^ (((a >> 9) & 7) << 4); }

// ---------------------------------------------------------------------------
// Prep: per c: G = W W^T + eps I ; chol G = L L^T ; Wt = L^{-1} W ;
// store Wt as bf16 in MFMA B-fragment order:
//   wfrag[kpass(2)][ntile(8)][k0(8)][lane(64)][j(8)]
//   value = Wt[cd = ntile*16 + (lane&15)][r = kpass*256 + k0*32 + (lane>>4)*8 + j]
// ---------------------------------------------------------------------------
__global__ void prep_kernel(const float* __restrict__ weight,
                            unsigned short* __restrict__ wfrag) {
    __shared__ float Wc[NUM_D * RECEPT];
    __shared__ float G[NUM_D][NUM_D];
    __shared__ float Lm[NUM_D][NUM_D];
    const int c = blockIdx.x;
    const int t = threadIdx.x;  // 64 threads
    const float* wsrc = weight + (size_t)c * NUM_D * RECEPT;
    for (int i = t; i < NUM_D * RECEPT; i += 64) Wc[i] = wsrc[i];
    __syncthreads();
    {
        int d = t >> 3, e = t & 7;
        float s = 0.f;
        for (int r = 0; r < RECEPT; ++r) s += Wc[d * RECEPT + r] * Wc[e * RECEPT + r];
        if (d == e) s += EPS_V;
        G[d][e] = s;
    }
    __syncthreads();
    if (t == 0) {
        for (int i = 0; i < NUM_D; ++i) {
            float diag = G[i][i];
            for (int k = 0; k < i; ++k) diag -= Lm[i][k] * Lm[i][k];
            float di = sqrtf(diag);
            Lm[i][i] = di;
            float inv = 1.f / di;
            for (int jj = i + 1; jj < NUM_D; ++jj) {
                float s = G[jj][i];
                for (int k = 0; k < i; ++k) s -= Lm[jj][k] * Lm[i][k];
                Lm[jj][i] = s * inv;
            }
        }
    }
    __syncthreads();
    for (int r = t; r < RECEPT; r += 64) {
        float y[NUM_D];
        for (int d = 0; d < NUM_D; ++d) {
            float s = Wc[d * RECEPT + r];
            for (int k = 0; k < d; ++k) s -= Lm[d][k] * y[k];
            y[d] = s / Lm[d][d];
        }
        const int kpass = r >> 8;
        const int k0 = (r >> 5) & 7;
        const int g  = (r >> 3) & 3;
        const int j  = r & 7;
        for (int d = 0; d < NUM_D; ++d) {
            int cd = c * NUM_D + d;
            int ntile = cd >> 4;
            int nl = cd & 15;
            int lane = g * 16 + nl;
            int idx = ((((kpass * 8 + ntile) * 8 + k0) * 64) + lane) * 8 + j;
            wfrag[idx] = f2bf(y[d]);
        }
    }
}

// ---------------------------------------------------------------------------
// Main: one block per b. 512 threads = 8 waves (2 M-groups x 4 N-groups).
// Wave tile 64x32 of the 128x128 output, acc persists over 2 K-passes.
// ---------------------------------------------------------------------------
__global__ __launch_bounds__(512, 2) void main_kernel(
        const float* __restrict__ x,
        const unsigned short* __restrict__ wfrag,
        float* __restrict__ out) {
    extern __shared__ char lds[];
    char* wl = lds + XBYTES;
    const int b = blockIdx.x;
    const int t = threadIdx.x;
    const int lane = t & 63;
    const int wv = t >> 6;
    const int wmb = (wv & 1) * 64;    // window (M) base for this wave
    const int wnb = (wv >> 1) * 32;   // cd (N) base for this wave

    const float4* xrow4 = reinterpret_cast<const float4*>(x + (size_t)b * LROW);

    // stage x row -> bf16 LDS (swizzled), coalesced float4 loads
    #pragma unroll
    for (int i = 0; i < 16; ++i) {
        int f4 = i * 512 + t;                 // float4 chunk index 0..8191
        float4 v = xrow4[f4];
        ushort4 h;
        h.x = f2bf(v.x); h.y = f2bf(v.y); h.z = f2bf(v.z); h.w = f2bf(v.w);
        *reinterpret_cast<ushort4*>(lds + xsw(f4 * 8)) = h;
    }
    if (t < 64) {                             // wrap replica: x[b][0:256]
        float4 v = xrow4[t];
        ushort4 h;
        h.x = f2bf(v.x); h.y = f2bf(v.y); h.z = f2bf(v.z); h.w = f2bf(v.w);
        *reinterpret_cast<ushort4*>(lds + xsw(65536 + t * 8)) = h;
    }

    f32x4 acc[4][2];
    #pragma unroll
    for (int mi = 0; mi < 4; ++mi)
        #pragma unroll
        for (int ni = 0; ni < 2; ++ni)
            acc[mi][ni] = (f32x4){0.f, 0.f, 0.f, 0.f};

    const int rl = lane & 15;   // A: row-in-tile ; B: col-in-tile ; D: col
    const int gl = lane >> 4;   // k-group

    for (int kpass = 0; kpass < 2; ++kpass) {
        __syncthreads();   // previous compute / x staging done before LDS overwrite
        // stage this K-pass's weights (64KB, already fragment-ordered) linearly
        const float4* wsrc = reinterpret_cast<const float4*>(wfrag + kpass * 32768);
        float4* wdst = reinterpret_cast<float4*>(wl);
        #pragma unroll
        for (int i = 0; i < 8; ++i) wdst[i * 512 + t] = wsrc[i * 512 + t];
        __syncthreads();

        #pragma unroll
        for (int k0 = 0; k0 < 8; ++k0) {
            short8 af[4], bfr[2];
            const int kabs = kpass * 256 + k0 * 32 + gl * 8;
            #pragma unroll
            for (int mi = 0; mi < 4; ++mi) {
                int w = wmb + mi * 16 + rl;
                af[mi] = *reinterpret_cast<const short8*>(lds + xsw((w * 256 + kabs) * 2));
            }
            #pragma unroll
            for (int ni = 0; ni < 2; ++ni) {
                int ntile = (wnb >> 4) + ni;
                bfr[ni] = *reinterpret_cast<const short8*>(
                    wl + ((ntile * 8 + k0) * 64 + lane) * 16);
            }
            #pragma unroll
            for (int mi = 0; mi < 4; ++mi)
                #pragma unroll
                for (int ni = 0; ni < 2; ++ni)
                    acc[mi][ni] = __builtin_amdgcn_mfma_f32_16x16x32_bf16(
                        af[mi], bfr[ni], acc[mi][ni], 0, 0, 0);
        }
    }

    // epilogue: q = sum over the 8 d-columns of P^2 (lanes differing in bits 0..2),
    // sqrt, then sum over this wave's 64 windows; 2 atomics per (wave, ni).
    #pragma unroll
    for (int ni = 0; ni < 2; ++ni) {
        float s = 0.f;
        #pragma unroll
        for (int mi = 0; mi < 4; ++mi) {
            #pragma unroll
            for (int r = 0; r < 4; ++r) {
                float p = acc[mi][ni][r];
                float q = p * p;
                q += __shfl_xor(q, 1);
                q += __shfl_xor(q, 2);
                q += __shfl_xor(q, 4);
                s += sqrtf(q);
            }
        }
        s += __shfl_xor(s, 16);
        s += __shfl_xor(s, 32);
        if (lane < 16 && (lane & 7) == 0) {
            int c = (wnb + ni * 16 + rl) >> 3;
            atomicAdd(&out[b * NUM_C + c], s * (1.0f / 128.0f));
        }
    }
}

extern "C" void kernel_launch(void* const* d_in, const int* in_sizes, int n_in,
                              void* d_out, int out_size, void* d_ws, size_t ws_size,
                              hipStream_t stream) {
    (void)in_sizes; (void)n_in; (void)ws_size;
    const float* x      = (const float*)d_in[0];
    const float* weight = (const float*)d_in[1];
    float* out = (float*)d_out;
    unsigned short* wfrag = (unsigned short*)d_ws;   // needs 128 KiB scratch

    hipMemsetAsync(d_out, 0, (size_t)out_size * sizeof(float), stream);
    prep_kernel<<<16, 64, 0, stream>>>(weight, wfrag);

    hipFuncSetAttribute(reinterpret_cast<const void*>(main_kernel),
                        hipFuncAttributeMaxDynamicSharedMemorySize, LDS_TOTAL);
    main_kernel<<<512, 512, LDS_TOTAL, stream>>>(x, wfrag, out);
}

// Round 2
// 36.827 us; speedup vs baseline: 1.2858x; 1.2858x over previous
//
#include <hip/hip_runtime.h>

#define NUM_C  16
#define NUM_D  8
#define RECEPT 512
#define NWIN   128
#define LROW   32768
#define EPS_V  1e-4f

// x LDS region: 32768 + 256 (wrap replica) bf16 elements = 66048 bytes
#define XBYTES 66048

typedef __attribute__((ext_vector_type(8))) short short8;
typedef __attribute__((ext_vector_type(4))) float f32x4;

__device__ __forceinline__ unsigned short f2bf(float f) {
    unsigned int u = __builtin_bit_cast(unsigned int, f);
    u += 0x7fffu + ((u >> 16) & 1u);   // round-to-nearest-even
    return (unsigned short)(u >> 16);
}

// XOR swizzle on byte address within the 1-D x LDS buffer (involution; both
// the staging writes and the A-fragment reads apply it).
__device__ __forceinline__ int xsw(int a) { return a ^ (((a >> 9) & 7) << 4); }

// ---------------------------------------------------------------------------
// Prep: per c: G = W W^T + eps I ; chol G = L L^T ; Wt = L^{-1} W ;
// store Wt as bf16 in MFMA B-fragment order:
//   wfrag[ntile(8)][kk(16)][lane(64)][j(8)]
//   value = Wt[cd = ntile*16 + (lane&15)][r = kk*32 + (lane>>4)*8 + j]
// Also zeroes d_out (so the graph needs no separate memset node).
// ---------------------------------------------------------------------------
__global__ void prep_kernel(const float* __restrict__ weight,
                            unsigned short* __restrict__ wfrag,
                            float* __restrict__ out) {
    __shared__ float Wc[NUM_D * RECEPT];
    __shared__ float G[NUM_D][NUM_D];
    __shared__ float Lm[NUM_D][NUM_D];
    const int c = blockIdx.x;
    const int t = threadIdx.x;  // 64 threads

    // zero d_out: 512*16 = 8192 floats over 16 blocks x 64 threads
    #pragma unroll
    for (int i = 0; i < 8; ++i) out[c * 64 + t + i * 1024] = 0.f;

    const float* wsrc = weight + (size_t)c * NUM_D * RECEPT;
    for (int i = t; i < NUM_D * RECEPT; i += 64) Wc[i] = wsrc[i];
    __syncthreads();
    {
        int d = t >> 3, e = t & 7;
        const float4* wd4 = reinterpret_cast<const float4*>(&Wc[d * RECEPT]);
        const float4* we4 = reinterpret_cast<const float4*>(&Wc[e * RECEPT]);
        float s = 0.f;
        #pragma unroll 4
        for (int r4 = 0; r4 < RECEPT / 4; ++r4) {
            float4 a = wd4[r4], bb = we4[r4];
            s += a.x * bb.x + a.y * bb.y + a.z * bb.z + a.w * bb.w;
        }
        if (d == e) s += EPS_V;
        G[d][e] = s;
    }
    __syncthreads();
    if (t == 0) {
        for (int i = 0; i < NUM_D; ++i) {
            float diag = G[i][i];
            for (int k = 0; k < i; ++k) diag -= Lm[i][k] * Lm[i][k];
            float di = sqrtf(diag);
            Lm[i][i] = di;
            float inv = 1.f / di;
            for (int jj = i + 1; jj < NUM_D; ++jj) {
                float s = G[jj][i];
                for (int k = 0; k < i; ++k) s -= Lm[jj][k] * Lm[i][k];
                Lm[jj][i] = s * inv;
            }
        }
    }
    __syncthreads();
    for (int r = t; r < RECEPT; r += 64) {
        float y[NUM_D];
        for (int d = 0; d < NUM_D; ++d) {
            float s = Wc[d * RECEPT + r];
            for (int k = 0; k < d; ++k) s -= Lm[d][k] * y[k];
            y[d] = s / Lm[d][d];
        }
        const int kk = r >> 5;          // 0..15
        const int g  = (r >> 3) & 3;    // k-group within 32
        const int j  = r & 7;
        for (int d = 0; d < NUM_D; ++d) {
            int cd = c * NUM_D + d;
            int ntile = cd >> 4;
            int nl = cd & 15;
            int lane = g * 16 + nl;
            int idx = (((ntile * 16 + kk) * 64) + lane) * 8 + j;
            wfrag[idx] = f2bf(y[d]);
        }
    }
}

// ---------------------------------------------------------------------------
// Main: one block per b. 512 threads = 8 waves (2 M-groups x 4 N-groups).
// x row staged to LDS (bf16, swizzled); B fragments read directly from
// global wfrag (128 KB, L2/L3-resident, shared by all blocks) -> no weight
// staging barriers, LDS = 66 KB -> 2 blocks/CU, all 512 blocks co-resident.
// ---------------------------------------------------------------------------
__global__ __launch_bounds__(512, 4) void main_kernel(
        const float* __restrict__ x,
        const unsigned short* __restrict__ wfrag,
        float* __restrict__ out) {
    extern __shared__ char lds[];
    const int b = blockIdx.x;
    const int t = threadIdx.x;
    const int lane = t & 63;
    const int wv = t >> 6;
    const int wmb = (wv & 1) * 64;    // window (M) base for this wave
    const int wnb = (wv >> 1) * 32;   // cd (N) base for this wave

    const float4* xrow4 = reinterpret_cast<const float4*>(x + (size_t)b * LROW);

    // stage x row -> bf16 LDS (swizzled), coalesced float4 loads
    #pragma unroll
    for (int i = 0; i < 16; ++i) {
        int f4 = i * 512 + t;                 // float4 chunk index 0..8191
        float4 v = xrow4[f4];
        ushort4 h;
        h.x = f2bf(v.x); h.y = f2bf(v.y); h.z = f2bf(v.z); h.w = f2bf(v.w);
        *reinterpret_cast<ushort4*>(lds + xsw(f4 * 8)) = h;
    }
    if (t < 64) {                             // wrap replica: x[b][0:256]
        float4 v = xrow4[t];
        ushort4 h;
        h.x = f2bf(v.x); h.y = f2bf(v.y); h.z = f2bf(v.z); h.w = f2bf(v.w);
        *reinterpret_cast<ushort4*>(lds + xsw(65536 + t * 8)) = h;
    }

    f32x4 acc[4][2];
    #pragma unroll
    for (int mi = 0; mi < 4; ++mi)
        #pragma unroll
        for (int ni = 0; ni < 2; ++ni)
            acc[mi][ni] = (f32x4){0.f, 0.f, 0.f, 0.f};

    const int rl = lane & 15;   // A: row-in-tile ; B: col-in-tile ; D: col
    const int gl = lane >> 4;   // k-group

    // per-lane B base pointers (element offsets; 1 kk step = 512 elements)
    const int nt0 = wnb >> 4;
    const unsigned short* bb0 = wfrag + ((size_t)(nt0 * 16) * 64 + lane) * 8;
    const unsigned short* bb1 = wfrag + ((size_t)((nt0 + 1) * 16) * 64 + lane) * 8;

    __syncthreads();

    #pragma unroll 2
    for (int kk = 0; kk < 16; ++kk) {
        short8 af[4], bf0, bf1;
        const int kb = kk * 64 + gl * 16;     // byte offset along k
        #pragma unroll
        for (int mi = 0; mi < 4; ++mi) {
            int w = wmb + mi * 16 + rl;
            af[mi] = *reinterpret_cast<const short8*>(lds + xsw(w * 512 + kb));
        }
        bf0 = *reinterpret_cast<const short8*>(bb0 + kk * 512);
        bf1 = *reinterpret_cast<const short8*>(bb1 + kk * 512);
        #pragma unroll
        for (int mi = 0; mi < 4; ++mi) {
            acc[mi][0] = __builtin_amdgcn_mfma_f32_16x16x32_bf16(af[mi], bf0, acc[mi][0], 0, 0, 0);
            acc[mi][1] = __builtin_amdgcn_mfma_f32_16x16x32_bf16(af[mi], bf1, acc[mi][1], 0, 0, 0);
        }
    }

    // epilogue: q = sum over the 8 d-columns of P^2 (lanes differing in bits
    // 0..2), sqrt, then sum over this wave's 64 windows; atomics into out.
    #pragma unroll
    for (int ni = 0; ni < 2; ++ni) {
        float s = 0.f;
        #pragma unroll
        for (int mi = 0; mi < 4; ++mi) {
            #pragma unroll
            for (int r = 0; r < 4; ++r) {
                float p = acc[mi][ni][r];
                float q = p * p;
                q += __shfl_xor(q, 1);
                q += __shfl_xor(q, 2);
                q += __shfl_xor(q, 4);
                s += sqrtf(q);
            }
        }
        s += __shfl_xor(s, 16);
        s += __shfl_xor(s, 32);
        if (lane < 16 && (lane & 7) == 0) {
            int c = (wnb + ni * 16 + lane) >> 3;
            atomicAdd(&out[b * NUM_C + c], s * (1.0f / 128.0f));
        }
    }
}

extern "C" void kernel_launch(void* const* d_in, const int* in_sizes, int n_in,
                              void* d_out, int out_size, void* d_ws, size_t ws_size,
                              hipStream_t stream) {
    (void)in_sizes; (void)n_in; (void)ws_size; (void)out_size;
    const float* x      = (const float*)d_in[0];
    const float* weight = (const float*)d_in[1];
    float* out = (float*)d_out;
    unsigned short* wfrag = (unsigned short*)d_ws;   // needs 128 KiB scratch

    prep_kernel<<<16, 64, 0, stream>>>(weight, wfrag, out);

    hipFuncSetAttribute(reinterpret_cast<const void*>(main_kernel),
                        hipFuncAttributeMaxDynamicSharedMemorySize, XBYTES);
    main_kernel<<<512, 512, XBYTES, stream>>>(x, wfrag, out);
}